// Round 5
// baseline (1031.722 us; speedup 1.0000x reference)
//
#include <hip/hip_runtime.h>

typedef _Float16 f16;
typedef f16 f16x4 __attribute__((ext_vector_type(4)));
typedef f16 f16x8 __attribute__((ext_vector_type(8)));
typedef float f32x4 __attribute__((ext_vector_type(4)));

#define MFMA16(a, b, c) __builtin_amdgcn_mfma_f32_16x16x16f16((a), (b), (c), 0, 0, 0)
#define MFMA32(a, b, c) __builtin_amdgcn_mfma_f32_16x16x32_f16((a), (b), (c), 0, 0, 0)

struct Meta   { int pi[5], ci[5], ni[5]; };
struct EmbMap { int m[9]; };

// ---------------- LayerNorm(+temporal emb) -> f16, 4 rows/block ----------------
template <int CIN>
__global__ __launch_bounds__(256) void ln_kernel(
    const float* in, long lda, const float* __restrict__ emb,
    const float* __restrict__ lng, const float* __restrict__ lnb,
    f16* out, long ldo, EmbMap em) {
  long row = (long)blockIdx.x * 4 + (threadIdx.x >> 6);
  int t = (int)(row >> 15);  // B*Y*X = 32768
  int lane = threadIdx.x & 63;
  constexpr int NCH = CIN / 64;
  const float* xr = in + row * lda;
  const float* er = emb + (long)em.m[t] * CIN;
  float v[NCH];
  float s = 0.f;
#pragma unroll
  for (int i = 0; i < NCH; ++i) { int c = lane + (i << 6); v[i] = xr[c] + er[c]; s += v[i]; }
#pragma unroll
  for (int o = 32; o >= 1; o >>= 1) s += __shfl_xor(s, o);
  float mu = s * (1.f / CIN), ss = 0.f;
#pragma unroll
  for (int i = 0; i < NCH; ++i) { float d = v[i] - mu; ss += d * d; }
#pragma unroll
  for (int o = 32; o >= 1; o >>= 1) ss += __shfl_xor(ss, o);
  float inv = rsqrtf(ss * (1.f / CIN) + 1e-3f);
  f16* orow = out + row * ldo;
#pragma unroll
  for (int i = 0; i < NCH; ++i) {
    int c = lane + (i << 6);
    orow[c] = (f16)((v[i] - mu) * inv * lng[c] + lnb[c]);
  }
}

// ---------------- wqkv transpose+convert ----------------
template <int CIN>
__global__ __launch_bounds__(64) void wT_kernel(const float* __restrict__ wqkv,
                                                f16* __restrict__ wqkvT) {
  int j = blockIdx.x;
  int which = j / CIN, jj = j % CIN;
  const float* src = wqkv + (long)which * CIN * CIN + jj;
  f16* dst = wqkvT + (long)j * CIN;
  for (int c = threadIdx.x; c < CIN; c += 64) dst[c] = (f16)src[(long)c * CIN];
}

// ---------------- fused out-proj weights ----------------
template <int CIN, int CO>
__global__ __launch_bounds__(256) void woc_kernel(
    const float* __restrict__ wo, const float* __restrict__ bo,
    const float* __restrict__ cw, const float* __restrict__ cb,
    f16* __restrict__ wocT, float* __restrict__ fb) {
  __shared__ float scw[4 * CIN];
  __shared__ float red[256];
  int o = blockIdx.x;
  for (int i = threadIdx.x; i < 4 * CIN; i += 256) scw[i] = cw[(long)i * CO + o];
  __syncthreads();
  for (int pm = threadIdx.x; pm < 4 * CIN; pm += 256) {
    int p = pm / CIN, mm = pm % CIN;
    const float* wr = wo + (long)mm * CIN;
    const float* sc = scw + p * CIN;
    float s = 0.f;
    for (int c = 0; c < CIN; ++c) s += wr[c] * sc[c];
    wocT[(long)o * 4 * CIN + pm] = (f16)s;
  }
  float part = 0.f;
  for (int i = threadIdx.x; i < 4 * CIN; i += 256) part += bo[i % CIN] * scw[i];
  red[threadIdx.x] = part;
  __syncthreads();
  for (int st = 128; st > 0; st >>= 1) {
    if (threadIdx.x < st) red[threadIdx.x] += red[threadIdx.x + st];
    __syncthreads();
  }
  if (threadIdx.x == 0) fb[o] = cb[o] + red[0];
}

// ---------------- QKV projection GEMM: one block = one window ----------------
// gq/gk: [win][64][CIN] row-major; gvt: [win][CIN][64] (V^T), full-column writes.
template <int CIN>
__global__ __launch_bounds__(256, 4) void proj_kernel(
    const f16* __restrict__ cur, long lda, const f16* __restrict__ wT,
    const float* __restrict__ bqkv, f16* __restrict__ gq, f16* __restrict__ gk,
    f16* __restrict__ gvt) {
  constexpr int KS = CIN / 32;
  constexpr int NT = CIN / 16;
  constexpr int C8 = CIN / 8;
  __shared__ f16 sO[64 * CIN];
  int which = blockIdx.x;
  long win = blockIdx.y;                 // img*256 + wid
  long img = win >> 8;
  int wid = (int)(win & 255);
  int wy = wid >> 4, wx = wid & 15;
  int w = threadIdx.x >> 6, lane = threadIdx.x & 63;
  int r16 = lane & 15, kq = lane >> 4;
  int tok = w * 16 + r16;
  long orig = img * 16384 + (long)(wy * 8 + (tok >> 3)) * 128 + wx * 8 + (tok & 7);
  const f16* arow = cur + orig * lda + kq * 8;
  const f16* bbase = wT + ((long)which * CIN + r16) * CIN + kq * 8;
  f32x4 acc[NT] = {};
#pragma unroll
  for (int ks = 0; ks < KS; ++ks) {
    f16x8 a = *(const f16x8*)(arow + ks * 32);
#pragma unroll
    for (int t = 0; t < NT; ++t) {
      f16x8 bb = *(const f16x8*)(bbase + t * 16 * CIN + ks * 32);
      acc[t] = MFMA32(a, bb, acc[t]);
    }
  }
  if (which < 2) {
    // stage row-major (XOR-swizzled) with bias, then coalesced row stores
#pragma unroll
    for (int t = 0; t < NT; ++t) {
      float bias = bqkv[which * CIN + t * 16 + r16];
#pragma unroll
      for (int rg = 0; rg < 4; ++rg) {
        int r = w * 16 + kq * 4 + rg;
        int c = t * 16 + r16;
        int off = ((r * CIN + c) * 2) ^ ((r & 7) << 4);
        *(f16*)((char*)sO + off) = (f16)(acc[t][rg] + bias);
      }
    }
    __syncthreads();
    f16* dst = (which ? gk : gq) + win * 64 * CIN;
    for (int idx = threadIdx.x; idx < 64 * C8; idx += 256) {
      int r = idx / C8, c8 = idx % C8;
      int off = ((r * CIN + c8 * 8) * 2) ^ ((r & 7) << 4);
      f16x8 v = *(const f16x8*)((char*)sO + off);
      *(f16x8*)(dst + r * CIN + c8 * 8) = v;
    }
  } else {
    // stage TRANSPOSED sV[c][pos] (XOR-swizzled), then full-column stores
#pragma unroll
    for (int t = 0; t < NT; ++t) {
      float bias = bqkv[2 * CIN + t * 16 + r16];
#pragma unroll
      for (int rg = 0; rg < 4; ++rg) {
        int c = t * 16 + r16;
        int pos = w * 16 + kq * 4 + rg;
        int off = ((c * 64 + pos) * 2) ^ ((c & 7) << 4);
        *(f16*)((char*)sO + off) = (f16)(acc[t][rg] + bias);
      }
    }
    __syncthreads();
    for (int c = threadIdx.x; c < CIN; c += 256) {
      f16* dst = gvt + (win * CIN + c) * 64;
#pragma unroll
      for (int p8 = 0; p8 < 8; ++p8) {
        int off = ((c * 64 + p8 * 8) * 2) ^ ((c & 7) << 4);
        *(f16x8*)(dst + p8 * 8) = *(const f16x8*)((char*)sO + off);
      }
    }
  }
}

// ---------------- fused window attention (swapped-MFMA, hoisted fragments) ----
template <int CIN, int DH, int CO>
__global__ __launch_bounds__(256) void attn_kernel(
    const f16* __restrict__ gq, const f16* __restrict__ gk,
    const f16* __restrict__ gvt, const f16* __restrict__ wocT,
    const float* __restrict__ fb, float* __restrict__ out, Meta m) {
  constexpr int NKS = DH / 16;
  constexpr int CO4 = CO / 4;
  constexpr int NTC = CO4 / 16;
  constexpr int NKD = CIN / 16;
  constexpr float scale = (DH == 16) ? 0.25f : (DH == 32) ? 0.1767766952966369f
                                                          : 0.1443375672974064f;
  __shared__ f16 O[64 * CIN];

  int img = blockIdx.y;
  int sidx = img >> 1, b = img & 1;
  int wid = blockIdx.x;
  int wy = wid >> 4, wx = wid & 15;
  int h = threadIdx.x >> 6, lane = threadIdx.x & 63;
  int r16 = lane & 15, kq = lane >> 4;
  long ciwin = (long)((m.ci[sidx] * 2 + b) * 256 + wid);
  long piwin = (long)((m.pi[sidx] * 2 + b) * 256 + wid);
  long niwin = (long)((m.ni[sidx] * 2 + b) * 256 + wid);

  f32x4 dn[NTC][4] = {};

  auto ldfrag = [&](const f16* base, long winI, f16x4 (&fr)[4][NKS]) {
#pragma unroll
    for (int t = 0; t < 4; ++t)
#pragma unroll
      for (int ks = 0; ks < NKS; ++ks)
        fr[t][ks] = *(const f16x4*)(base + (winI * 64 + t * 16 + r16) * CIN +
                                    h * DH + ks * 16 + kq * 4);
  };

  auto do_part = [&](f16x4 (&kf)[4][NKS], f16x4 (&qf)[4][NKS], long vwin, int p) {
    // ---- S^T = K * Q^T ----
    f32x4 sc[4][4] = {};  // [tj][ti]
#pragma unroll
    for (int ti = 0; ti < 4; ++ti)
#pragma unroll
      for (int tj = 0; tj < 4; ++tj)
#pragma unroll
        for (int ks = 0; ks < NKS; ++ks)
          sc[tj][ti] = MFMA16(kf[tj][ks], qf[ti][ks], sc[tj][ti]);

    // ---- softmax over j (regs + xor16/32) ----
    f16x4 pa[4][4];  // [tj][ti]
#pragma unroll
    for (int ti = 0; ti < 4; ++ti) {
      float mx = -1e30f;
#pragma unroll
      for (int tj = 0; tj < 4; ++tj)
#pragma unroll
        for (int rg = 0; rg < 4; ++rg) mx = fmaxf(mx, sc[tj][ti][rg]);
      mx = fmaxf(mx, __shfl_xor(mx, 16));
      mx = fmaxf(mx, __shfl_xor(mx, 32));
      float sum = 0.f;
#pragma unroll
      for (int tj = 0; tj < 4; ++tj)
#pragma unroll
        for (int rg = 0; rg < 4; ++rg) {
          float e = __expf((sc[tj][ti][rg] - mx) * scale);
          sc[tj][ti][rg] = e;
          sum += e;
        }
      sum += __shfl_xor(sum, 16);
      sum += __shfl_xor(sum, 32);
      float inv = 1.f / sum;
#pragma unroll
      for (int tj = 0; tj < 4; ++tj) {
        f16x4 pv;
#pragma unroll
        for (int rg = 0; rg < 4; ++rg) pv[rg] = (f16)(sc[tj][ti][rg] * inv);
        pa[tj][ti] = pv;
      }
    }

    // ---- O^T = V^T * P^T -> LDS O (XOR-swizzled) ----
#pragma unroll
    for (int dt = 0; dt < NKS; ++dt) {
      f16x4 va[4];
#pragma unroll
      for (int jt = 0; jt < 4; ++jt)
        va[jt] = *(const f16x4*)(gvt + (vwin * CIN + h * DH + dt * 16 + r16) * 64 +
                                 jt * 16 + kq * 4);
#pragma unroll
      for (int ti = 0; ti < 4; ++ti) {
        f32x4 po = {};
#pragma unroll
        for (int jt = 0; jt < 4; ++jt) po = MFMA16(va[jt], pa[jt][ti], po);
        int i = ti * 16 + r16;
        int c0 = h * DH + dt * 16 + kq * 4;
        f16x4 pk;
#pragma unroll
        for (int rg = 0; rg < 4; ++rg) pk[rg] = (f16)po[rg];
        int off = ((i * CIN + c0) * 2) ^ ((i & 7) << 4);
        *(f16x4*)((char*)O + off) = pk;
      }
    }
    __syncthreads();

    // ---- dn^T += woc_p^T * O^T ----
#pragma unroll
    for (int ck = 0; ck < NKD; ++ck) {
      f16x4 ob[4];
#pragma unroll
      for (int ti = 0; ti < 4; ++ti) {
        int i = ti * 16 + r16;
        int off = ((i * CIN + ck * 16 + kq * 4) * 2) ^ ((i & 7) << 4);
        ob[ti] = *(const f16x4*)((char*)O + off);
      }
#pragma unroll
      for (int ot = 0; ot < NTC; ++ot) {
        f16x4 wa = *(const f16x4*)(wocT + ((long)(h * CO4 + ot * 16 + r16)) * 4 * CIN +
                                   p * CIN + ck * 16 + kq * 4);
#pragma unroll
        for (int ti = 0; ti < 4; ++ti) dn[ot][ti] = MFMA16(wa, ob[ti], dn[ot][ti]);
      }
    }
    __syncthreads();  // before next part overwrites O
  };

  f16x4 fA[4][NKS], fB[4][NKS];
  ldfrag(gq, ciwin, fA);                       // Q of ci (parts 0,2)
  ldfrag(gk, piwin, fB); do_part(fB, fA, piwin, 0);
  ldfrag(gk, niwin, fB); do_part(fB, fA, niwin, 2);
  ldfrag(gk, ciwin, fA);                       // K of ci (parts 1,3)
  ldfrag(gq, piwin, fB); do_part(fA, fB, ciwin, 1);
  ldfrag(gq, niwin, fB); do_part(fA, fB, ciwin, 3);

  // ---- store: relu(dn + fb), packed f32x4 ----
#pragma unroll
  for (int ot = 0; ot < NTC; ++ot) {
    f32x4 fb4 = *(const f32x4*)(fb + h * CO4 + ot * 16 + kq * 4);
#pragma unroll
    for (int ti = 0; ti < 4; ++ti) {
      int i = ti * 16 + r16;
      long gtok = (long)img * 16384 + (wy * 8 + (i >> 3)) * 128 + wx * 8 + (i & 7);
      f32x4 v;
#pragma unroll
      for (int rg = 0; rg < 4; ++rg) v[rg] = fmaxf(dn[ot][ti][rg] + fb4[rg], 0.f);
      *(f32x4*)(out + gtok * CO + h * CO4 + ot * 16 + kq * 4) = v;
    }
  }
}

extern "C" void kernel_launch(void* const* d_in, const int* in_sizes, int n_in,
                              void* d_out, int out_size, void* d_ws, size_t ws_size,
                              hipStream_t stream) {
  const float* x = (const float*)d_in[0];
#define PRM(l, k) ((const float*)d_in[1 + 9 * (l) + (k)])
  float* outCur = (float*)d_out;                 // [2,128,128,256]
  float* outL1 = (float*)d_out + 8388608;        // [5,2,128,128,128]

  char* ws = (char*)d_ws;
  const size_t OFF_B = 125829120ull;             // qkv arena
  const size_t OFF_W = OFF_B + 75497472ull;      // cur / accum1 arena
  f16* qkvbase = (f16*)ws;
  char* wsB = ws + OFF_B;
  float* accum1 = (float*)wsB;
  f16* wqkvT = (f16*)(ws + OFF_W);
  f16* wocT = (f16*)(ws + OFF_W + 262144);
  float* fb = (float*)(ws + OFF_W + 262144 + 524288);

  Meta m0 = {{0, 1, 3, 5, 6}, {1, 2, 4, 6, 7}, {2, 3, 5, 7, 8}};
  Meta m1 = {{0, 1, 2, 0, 0}, {1, 2, 3, 0, 0}, {2, 3, 4, 0, 0}};
  Meta m2 = {{0, 0, 0, 0, 0}, {1, 0, 0, 0, 0}, {2, 0, 0, 0, 0}};
  EmbMap em0 = {{0, 1, 2, 3, 4, 5, 6, 7, 8}};
  EmbMap em1 = {{1, 2, 4, 6, 7, 0, 0, 0, 0}};
  EmbMap em2 = {{2, 4, 6, 0, 0, 0, 0, 0, 0}};

  // ---------------- Level 0: CIN=64, DH=16, CO=128, TL=9, S=5 ----------------
  {
    constexpr int CIN = 64, DH = 16, CO = 128, TL = 9, S = 5;
    long ntok = (long)TL * 2 * 16384;
    f16 *gq = qkvbase, *gk = gq + ntok * CIN, *gvt = gk + ntok * CIN;
    f16* cur = (f16*)wsB;
    ln_kernel<CIN><<<dim3((unsigned)(ntok / 4)), 256, 0, stream>>>(
        x, CIN, PRM(0, 0), PRM(0, 1), PRM(0, 2), cur, CIN, em0);
    wT_kernel<CIN><<<dim3(3 * CIN), 64, 0, stream>>>(PRM(0, 3), wqkvT);
    woc_kernel<CIN, CO><<<dim3(CO), 256, 0, stream>>>(PRM(0, 5), PRM(0, 6), PRM(0, 7), PRM(0, 8), wocT, fb);
    proj_kernel<CIN><<<dim3(3, (unsigned)(ntok / 64)), 256, 0, stream>>>(
        cur, CIN, wqkvT, PRM(0, 4), gq, gk, gvt);
    attn_kernel<CIN, DH, CO><<<dim3(256, S * 2), 256, 0, stream>>>(
        gq, gk, gvt, wocT, fb, outL1, m0);
  }
  // ---------------- Level 1: CIN=128, DH=32, CO=192, TL=5, S=3 ----------------
  {
    constexpr int CIN = 128, DH = 32, CO = 192, TL = 5, S = 3;
    long ntok = (long)TL * 2 * 16384;
    f16 *gq = qkvbase, *gk = gq + ntok * CIN, *gvt = gk + ntok * CIN;
    f16* cur = (f16*)wsB;
    ln_kernel<CIN><<<dim3((unsigned)(ntok / 4)), 256, 0, stream>>>(
        outL1, CIN, PRM(1, 0), PRM(1, 1), PRM(1, 2), cur, CIN, em1);
    wT_kernel<CIN><<<dim3(3 * CIN), 64, 0, stream>>>(PRM(1, 3), wqkvT);
    woc_kernel<CIN, CO><<<dim3(CO), 256, 0, stream>>>(PRM(1, 5), PRM(1, 6), PRM(1, 7), PRM(1, 8), wocT, fb);
    proj_kernel<CIN><<<dim3(3, (unsigned)(ntok / 64)), 256, 0, stream>>>(
        cur, CIN, wqkvT, PRM(1, 4), gq, gk, gvt);
    attn_kernel<CIN, DH, CO><<<dim3(256, S * 2), 256, 0, stream>>>(
        gq, gk, gvt, wocT, fb, accum1, m1);
  }
  // ---------------- Level 2: CIN=192, DH=48, CO=256, TL=3, S=1 ----------------
  {
    constexpr int CIN = 192, DH = 48, CO = 256, TL = 3, S = 1;
    long ntok = (long)TL * 2 * 16384;
    f16 *gq = qkvbase, *gk = gq + ntok * CIN, *gvt = gk + ntok * CIN;
    f16* cur = (f16*)accum1;  // in-place LN: fp32 rows (stride 192) -> f16 (stride 384)
    ln_kernel<CIN><<<dim3((unsigned)(ntok / 4)), 256, 0, stream>>>(
        accum1, CIN, PRM(2, 0), PRM(2, 1), PRM(2, 2), cur, 384, em2);
    wT_kernel<CIN><<<dim3(3 * CIN), 64, 0, stream>>>(PRM(2, 3), wqkvT);
    woc_kernel<CIN, CO><<<dim3(CO), 256, 0, stream>>>(PRM(2, 5), PRM(2, 6), PRM(2, 7), PRM(2, 8), wocT, fb);
    proj_kernel<CIN><<<dim3(3, (unsigned)(ntok / 64)), 256, 0, stream>>>(
        cur, 384, wqkvT, PRM(2, 4), gq, gk, gvt);
    attn_kernel<CIN, DH, CO><<<dim3(256, S * 2), 256, 0, stream>>>(
        gq, gk, gvt, wocT, fb, outCur, m2);
  }
#undef PRM
}

// Round 6
// 690.798 us; speedup vs baseline: 1.4935x; 1.4935x over previous
//
#include <hip/hip_runtime.h>

typedef _Float16 f16;
typedef f16 f16x4 __attribute__((ext_vector_type(4)));
typedef f16 f16x8 __attribute__((ext_vector_type(8)));
typedef float f32x4 __attribute__((ext_vector_type(4)));

#define MFMA16(a, b, c) __builtin_amdgcn_mfma_f32_16x16x16f16((a), (b), (c), 0, 0, 0)
#define MFMA32(a, b, c) __builtin_amdgcn_mfma_f32_16x16x32_f16((a), (b), (c), 0, 0, 0)

struct Meta   { int pi[5], ci[5], ni[5]; };
struct EmbMap { int m[9]; };

// ---------------- LayerNorm(+temporal emb) -> f16, 4 rows/block ----------------
template <int CIN>
__global__ __launch_bounds__(256) void ln_kernel(
    const float* in, long lda, const float* __restrict__ emb,
    const float* __restrict__ lng, const float* __restrict__ lnb,
    f16* out, long ldo, EmbMap em) {
  long row = (long)blockIdx.x * 4 + (threadIdx.x >> 6);
  int t = (int)(row >> 15);  // B*Y*X = 32768
  int lane = threadIdx.x & 63;
  constexpr int NCH = CIN / 64;
  const float* xr = in + row * lda;
  const float* er = emb + (long)em.m[t] * CIN;
  float v[NCH];
  float s = 0.f;
#pragma unroll
  for (int i = 0; i < NCH; ++i) { int c = lane + (i << 6); v[i] = xr[c] + er[c]; s += v[i]; }
#pragma unroll
  for (int o = 32; o >= 1; o >>= 1) s += __shfl_xor(s, o);
  float mu = s * (1.f / CIN), ss = 0.f;
#pragma unroll
  for (int i = 0; i < NCH; ++i) { float d = v[i] - mu; ss += d * d; }
#pragma unroll
  for (int o = 32; o >= 1; o >>= 1) ss += __shfl_xor(ss, o);
  float inv = rsqrtf(ss * (1.f / CIN) + 1e-3f);
  f16* orow = out + row * ldo;
#pragma unroll
  for (int i = 0; i < NCH; ++i) {
    int c = lane + (i << 6);
    orow[c] = (f16)((v[i] - mu) * inv * lng[c] + lnb[c]);
  }
}

// ---------------- wqkv transpose+convert ----------------
template <int CIN>
__global__ __launch_bounds__(64) void wT_kernel(const float* __restrict__ wqkv,
                                                f16* __restrict__ wqkvT) {
  int j = blockIdx.x;
  int which = j / CIN, jj = j % CIN;
  const float* src = wqkv + (long)which * CIN * CIN + jj;
  f16* dst = wqkvT + (long)j * CIN;
  for (int c = threadIdx.x; c < CIN; c += 64) dst[c] = (f16)src[(long)c * CIN];
}

// ---------------- fused out-proj weights ----------------
template <int CIN, int CO>
__global__ __launch_bounds__(256) void woc_kernel(
    const float* __restrict__ wo, const float* __restrict__ bo,
    const float* __restrict__ cw, const float* __restrict__ cb,
    f16* __restrict__ wocT, float* __restrict__ fb) {
  __shared__ float scw[4 * CIN];
  __shared__ float red[256];
  int o = blockIdx.x;
  for (int i = threadIdx.x; i < 4 * CIN; i += 256) scw[i] = cw[(long)i * CO + o];
  __syncthreads();
  for (int pm = threadIdx.x; pm < 4 * CIN; pm += 256) {
    int p = pm / CIN, mm = pm % CIN;
    const float* wr = wo + (long)mm * CIN;
    const float* sc = scw + p * CIN;
    float s = 0.f;
    for (int c = 0; c < CIN; ++c) s += wr[c] * sc[c];
    wocT[(long)o * 4 * CIN + pm] = (f16)s;
  }
  float part = 0.f;
  for (int i = threadIdx.x; i < 4 * CIN; i += 256) part += bo[i % CIN] * scw[i];
  red[threadIdx.x] = part;
  __syncthreads();
  for (int st = 128; st > 0; st >>= 1) {
    if (threadIdx.x < st) red[threadIdx.x] += red[threadIdx.x + st];
    __syncthreads();
  }
  if (threadIdx.x == 0) fb[o] = cb[o] + red[0];
}

// ---------------- QKV projection GEMM: weights in LDS, one block = one window --
// gq/gk: [win][64][CIN] row-major; gvt: [win][CIN][64] (V^T), full-column writes.
// sB holds wT[which] (XOR-swizzled); after MFMA it is reused as output staging.
template <int CIN>
__global__ __launch_bounds__(256) void proj_kernel(
    const f16* __restrict__ cur, long lda, const f16* __restrict__ wT,
    const float* __restrict__ bqkv, f16* __restrict__ gq, f16* __restrict__ gk,
    f16* __restrict__ gvt) {
  constexpr int KS = CIN / 32;
  constexpr int NT = CIN / 16;
  constexpr int C8 = CIN / 8;
  __shared__ f16 sB[CIN * CIN];
  int which = blockIdx.x;
  long win = blockIdx.y;                 // img*256 + wid
  long img = win >> 8;
  int wid = (int)(win & 255);
  int wy = wid >> 4, wx = wid & 15;
  int w = threadIdx.x >> 6, lane = threadIdx.x & 63;
  int r16 = lane & 15, kq = lane >> 4;

  // A fragments into registers first (overlaps with weight staging below)
  int tok = w * 16 + r16;
  long orig = img * 16384 + (long)(wy * 8 + (tok >> 3)) * 128 + wx * 8 + (tok & 7);
  const f16* arow = cur + orig * lda + kq * 8;
  f16x8 a[KS];
#pragma unroll
  for (int ks = 0; ks < KS; ++ks) a[ks] = *(const f16x8*)(arow + ks * 32);

  // cooperative weight load -> LDS (coalesced global, swizzled LDS rows)
  const f16* wsrc = wT + (long)which * CIN * CIN;
  for (int idx = threadIdx.x; idx < CIN * C8; idx += 256) {
    int j = idx / C8, c8 = idx % C8;
    f16x8 v = *(const f16x8*)(wsrc + idx * 8);
    int off = ((j * CIN + c8 * 8) * 2) ^ ((j & 7) << 4);
    *(f16x8*)((char*)sB + off) = v;
  }
  __syncthreads();

  f32x4 acc[NT] = {};
#pragma unroll
  for (int ks = 0; ks < KS; ++ks) {
#pragma unroll
    for (int t = 0; t < NT; ++t) {
      int off = (((t * 16 + r16) * CIN + ks * 32 + kq * 8) * 2) ^ ((r16 & 7) << 4);
      f16x8 bb = *(const f16x8*)((char*)sB + off);
      acc[t] = MFMA32(a[ks], bb, acc[t]);
    }
  }
  __syncthreads();  // weights no longer needed; reuse sB as output staging

  if (which < 2) {
    // stage row-major (XOR-swizzled) with bias, then coalesced row stores
#pragma unroll
    for (int t = 0; t < NT; ++t) {
      float bias = bqkv[which * CIN + t * 16 + r16];
#pragma unroll
      for (int rg = 0; rg < 4; ++rg) {
        int r = w * 16 + kq * 4 + rg;
        int c = t * 16 + r16;
        int off = ((r * CIN + c) * 2) ^ ((r & 7) << 4);
        *(f16*)((char*)sB + off) = (f16)(acc[t][rg] + bias);
      }
    }
    __syncthreads();
    f16* dst = (which ? gk : gq) + win * 64 * CIN;
    for (int idx = threadIdx.x; idx < 64 * C8; idx += 256) {
      int r = idx / C8, c8 = idx % C8;
      int off = ((r * CIN + c8 * 8) * 2) ^ ((r & 7) << 4);
      f16x8 v = *(const f16x8*)((char*)sB + off);
      *(f16x8*)(dst + r * CIN + c8 * 8) = v;
    }
  } else {
    // stage TRANSPOSED sV[c][pos] (XOR-swizzled), then full-column stores
#pragma unroll
    for (int t = 0; t < NT; ++t) {
      float bias = bqkv[2 * CIN + t * 16 + r16];
#pragma unroll
      for (int rg = 0; rg < 4; ++rg) {
        int c = t * 16 + r16;
        int pos = w * 16 + kq * 4 + rg;
        int off = ((c * 64 + pos) * 2) ^ ((c & 7) << 4);
        *(f16*)((char*)sB + off) = (f16)(acc[t][rg] + bias);
      }
    }
    __syncthreads();
    for (int c = threadIdx.x; c < CIN; c += 256) {
      f16* dst = gvt + (win * CIN + c) * 64;
#pragma unroll
      for (int p8 = 0; p8 < 8; ++p8) {
        int off = ((c * 64 + p8 * 8) * 2) ^ ((c & 7) << 4);
        *(f16x8*)(dst + p8 * 8) = *(const f16x8*)((char*)sB + off);
      }
    }
  }
}

// ---------------- fused window attention (swapped-MFMA chain, R4 version) -----
// Block = one window of one (s,b); wave = head; all 4 parts, single fp32 write.
template <int CIN, int DH, int CO>
__global__ __launch_bounds__(256) void attn_kernel(
    const f16* __restrict__ gq, const f16* __restrict__ gk,
    const f16* __restrict__ gvt, const f16* __restrict__ wocT,
    const float* __restrict__ fb, float* __restrict__ out, Meta m) {
  constexpr int NKS = DH / 16;
  constexpr int CO4 = CO / 4;
  constexpr int NTC = CO4 / 16;
  constexpr int NKD = CIN / 16;
  constexpr float scale = (DH == 16) ? 0.25f : (DH == 32) ? 0.1767766952966369f
                                                          : 0.1443375672974064f;
  __shared__ f16 O[64 * CIN];

  int img = blockIdx.y;
  int sidx = img >> 1, b = img & 1;
  int wid = blockIdx.x;
  int wy = wid >> 4, wx = wid & 15;
  int h = threadIdx.x >> 6, lane = threadIdx.x & 63;
  int r16 = lane & 15, kq = lane >> 4;
  int fpi = m.pi[sidx], fci = m.ci[sidx], fni = m.ni[sidx];

  f32x4 dn[NTC][4] = {};

  for (int p = 0; p < 4; ++p) {
    int qfr = (p == 1) ? fpi : ((p == 3) ? fni : fci);
    int kfr = (p == 0) ? fpi : ((p == 2) ? fni : fci);
    long qwin = (long)((qfr * 2 + b) * 256 + wid);
    long kwin = (long)((kfr * 2 + b) * 256 + wid);

    // ---- S^T = K * Q^T : lane holds S^T[j][i] ----
    f16x4 kf[4][NKS];
#pragma unroll
    for (int tj = 0; tj < 4; ++tj)
#pragma unroll
      for (int ks = 0; ks < NKS; ++ks)
        kf[tj][ks] = *(const f16x4*)(gk + (kwin * 64 + tj * 16 + r16) * CIN +
                                     h * DH + ks * 16 + kq * 4);
    f32x4 sc[4][4] = {};  // [tj][ti]
#pragma unroll
    for (int ti = 0; ti < 4; ++ti) {
      f16x4 qf[NKS];
#pragma unroll
      for (int ks = 0; ks < NKS; ++ks)
        qf[ks] = *(const f16x4*)(gq + (qwin * 64 + ti * 16 + r16) * CIN +
                                 h * DH + ks * 16 + kq * 4);
#pragma unroll
      for (int tj = 0; tj < 4; ++tj)
#pragma unroll
        for (int ks = 0; ks < NKS; ++ks)
          sc[tj][ti] = MFMA16(kf[tj][ks], qf[ks], sc[tj][ti]);
    }

    // ---- softmax over j (regs + xor16/32); P stays in registers ----
    f16x4 pa[4][4];  // [tj][ti]
#pragma unroll
    for (int ti = 0; ti < 4; ++ti) {
      float mx = -1e30f;
#pragma unroll
      for (int tj = 0; tj < 4; ++tj)
#pragma unroll
        for (int rg = 0; rg < 4; ++rg) mx = fmaxf(mx, sc[tj][ti][rg]);
      mx = fmaxf(mx, __shfl_xor(mx, 16));
      mx = fmaxf(mx, __shfl_xor(mx, 32));
      float sum = 0.f;
#pragma unroll
      for (int tj = 0; tj < 4; ++tj)
#pragma unroll
        for (int rg = 0; rg < 4; ++rg) {
          float e = __expf((sc[tj][ti][rg] - mx) * scale);
          sc[tj][ti][rg] = e;
          sum += e;
        }
      sum += __shfl_xor(sum, 16);
      sum += __shfl_xor(sum, 32);
      float inv = 1.f / sum;
#pragma unroll
      for (int tj = 0; tj < 4; ++tj) {
        f16x4 pv;
#pragma unroll
        for (int rg = 0; rg < 4; ++rg) pv[rg] = (f16)(sc[tj][ti][rg] * inv);
        pa[tj][ti] = pv;
      }
    }

    // ---- O^T = V^T * P^T -> LDS O (XOR-swizzled) ----
#pragma unroll
    for (int dt = 0; dt < NKS; ++dt) {
      f16x4 va[4];
#pragma unroll
      for (int jt = 0; jt < 4; ++jt)
        va[jt] = *(const f16x4*)(gvt + (kwin * CIN + h * DH + dt * 16 + r16) * 64 +
                                 jt * 16 + kq * 4);
#pragma unroll
      for (int ti = 0; ti < 4; ++ti) {
        f32x4 po = {};
#pragma unroll
        for (int jt = 0; jt < 4; ++jt) po = MFMA16(va[jt], pa[jt][ti], po);
        int i = ti * 16 + r16;
        int c0 = h * DH + dt * 16 + kq * 4;
        f16x4 pk;
#pragma unroll
        for (int rg = 0; rg < 4; ++rg) pk[rg] = (f16)po[rg];
        int off = ((i * CIN + c0) * 2) ^ ((i & 7) << 4);
        *(f16x4*)((char*)O + off) = pk;
      }
    }
    __syncthreads();

    // ---- dn^T += woc_p^T * O^T ----
#pragma unroll
    for (int ck = 0; ck < NKD; ++ck) {
      f16x4 ob[4];
#pragma unroll
      for (int ti = 0; ti < 4; ++ti) {
        int i = ti * 16 + r16;
        int off = ((i * CIN + ck * 16 + kq * 4) * 2) ^ ((i & 7) << 4);
        ob[ti] = *(const f16x4*)((char*)O + off);
      }
#pragma unroll
      for (int ot = 0; ot < NTC; ++ot) {
        f16x4 wa = *(const f16x4*)(wocT + ((long)(h * CO4 + ot * 16 + r16)) * 4 * CIN +
                                   p * CIN + ck * 16 + kq * 4);
#pragma unroll
        for (int ti = 0; ti < 4; ++ti) dn[ot][ti] = MFMA16(wa, ob[ti], dn[ot][ti]);
      }
    }
    __syncthreads();  // before next part overwrites O
  }

  // ---- store: relu(dn + fb), packed f32x4 ----
#pragma unroll
  for (int ot = 0; ot < NTC; ++ot) {
    f32x4 fb4 = *(const f32x4*)(fb + h * CO4 + ot * 16 + kq * 4);
#pragma unroll
    for (int ti = 0; ti < 4; ++ti) {
      int i = ti * 16 + r16;
      long gtok = (long)img * 16384 + (wy * 8 + (i >> 3)) * 128 + wx * 8 + (i & 7);
      f32x4 v;
#pragma unroll
      for (int rg = 0; rg < 4; ++rg) v[rg] = fmaxf(dn[ot][ti][rg] + fb4[rg], 0.f);
      *(f32x4*)(out + gtok * CO + h * CO4 + ot * 16 + kq * 4) = v;
    }
  }
}

extern "C" void kernel_launch(void* const* d_in, const int* in_sizes, int n_in,
                              void* d_out, int out_size, void* d_ws, size_t ws_size,
                              hipStream_t stream) {
  const float* x = (const float*)d_in[0];
#define PRM(l, k) ((const float*)d_in[1 + 9 * (l) + (k)])
  float* outCur = (float*)d_out;                 // [2,128,128,256]
  float* outL1 = (float*)d_out + 8388608;        // [5,2,128,128,128]

  char* ws = (char*)d_ws;
  const size_t OFF_B = 125829120ull;             // qkv arena
  const size_t OFF_W = OFF_B + 75497472ull;      // cur / accum1 arena
  f16* qkvbase = (f16*)ws;
  char* wsB = ws + OFF_B;
  float* accum1 = (float*)wsB;
  f16* wqkvT = (f16*)(ws + OFF_W);
  f16* wocT = (f16*)(ws + OFF_W + 262144);
  float* fb = (float*)(ws + OFF_W + 262144 + 524288);

  Meta m0 = {{0, 1, 3, 5, 6}, {1, 2, 4, 6, 7}, {2, 3, 5, 7, 8}};
  Meta m1 = {{0, 1, 2, 0, 0}, {1, 2, 3, 0, 0}, {2, 3, 4, 0, 0}};
  Meta m2 = {{0, 0, 0, 0, 0}, {1, 0, 0, 0, 0}, {2, 0, 0, 0, 0}};
  EmbMap em0 = {{0, 1, 2, 3, 4, 5, 6, 7, 8}};
  EmbMap em1 = {{1, 2, 4, 6, 7, 0, 0, 0, 0}};
  EmbMap em2 = {{2, 4, 6, 0, 0, 0, 0, 0, 0}};

  // ---------------- Level 0: CIN=64, DH=16, CO=128, TL=9, S=5 ----------------
  {
    constexpr int CIN = 64, DH = 16, CO = 128, TL = 9, S = 5;
    long ntok = (long)TL * 2 * 16384;
    f16 *gq = qkvbase, *gk = gq + ntok * CIN, *gvt = gk + ntok * CIN;
    f16* cur = (f16*)wsB;
    ln_kernel<CIN><<<dim3((unsigned)(ntok / 4)), 256, 0, stream>>>(
        x, CIN, PRM(0, 0), PRM(0, 1), PRM(0, 2), cur, CIN, em0);
    wT_kernel<CIN><<<dim3(3 * CIN), 64, 0, stream>>>(PRM(0, 3), wqkvT);
    woc_kernel<CIN, CO><<<dim3(CO), 256, 0, stream>>>(PRM(0, 5), PRM(0, 6), PRM(0, 7), PRM(0, 8), wocT, fb);
    proj_kernel<CIN><<<dim3(3, (unsigned)(ntok / 64)), 256, 0, stream>>>(
        cur, CIN, wqkvT, PRM(0, 4), gq, gk, gvt);
    attn_kernel<CIN, DH, CO><<<dim3(256, S * 2), 256, 0, stream>>>(
        gq, gk, gvt, wocT, fb, outL1, m0);
  }
  // ---------------- Level 1: CIN=128, DH=32, CO=192, TL=5, S=3 ----------------
  {
    constexpr int CIN = 128, DH = 32, CO = 192, TL = 5, S = 3;
    long ntok = (long)TL * 2 * 16384;
    f16 *gq = qkvbase, *gk = gq + ntok * CIN, *gvt = gk + ntok * CIN;
    f16* cur = (f16*)wsB;
    ln_kernel<CIN><<<dim3((unsigned)(ntok / 4)), 256, 0, stream>>>(
        outL1, CIN, PRM(1, 0), PRM(1, 1), PRM(1, 2), cur, CIN, em1);
    wT_kernel<CIN><<<dim3(3 * CIN), 64, 0, stream>>>(PRM(1, 3), wqkvT);
    woc_kernel<CIN, CO><<<dim3(CO), 256, 0, stream>>>(PRM(1, 5), PRM(1, 6), PRM(1, 7), PRM(1, 8), wocT, fb);
    proj_kernel<CIN><<<dim3(3, (unsigned)(ntok / 64)), 256, 0, stream>>>(
        cur, CIN, wqkvT, PRM(1, 4), gq, gk, gvt);
    attn_kernel<CIN, DH, CO><<<dim3(256, S * 2), 256, 0, stream>>>(
        gq, gk, gvt, wocT, fb, accum1, m1);
  }
  // ---------------- Level 2: CIN=192, DH=48, CO=256, TL=3, S=1 ----------------
  {
    constexpr int CIN = 192, DH = 48, CO = 256, TL = 3, S = 1;
    long ntok = (long)TL * 2 * 16384;
    f16 *gq = qkvbase, *gk = gq + ntok * CIN, *gvt = gk + ntok * CIN;
    f16* cur = (f16*)accum1;  // in-place LN: fp32 rows (stride 192) -> f16 (stride 384)
    ln_kernel<CIN><<<dim3((unsigned)(ntok / 4)), 256, 0, stream>>>(
        accum1, CIN, PRM(2, 0), PRM(2, 1), PRM(2, 2), cur, 384, em2);
    wT_kernel<CIN><<<dim3(3 * CIN), 64, 0, stream>>>(PRM(2, 3), wqkvT);
    woc_kernel<CIN, CO><<<dim3(CO), 256, 0, stream>>>(PRM(2, 5), PRM(2, 6), PRM(2, 7), PRM(2, 8), wocT, fb);
    proj_kernel<CIN><<<dim3(3, (unsigned)(ntok / 64)), 256, 0, stream>>>(
        cur, 384, wqkvT, PRM(2, 4), gq, gk, gvt);
    attn_kernel<CIN, DH, CO><<<dim3(256, S * 2), 256, 0, stream>>>(
        gq, gk, gvt, wocT, fb, outCur, m2);
  }
#undef PRM
}

// Round 7
// 629.798 us; speedup vs baseline: 1.6382x; 1.0969x over previous
//
#include <hip/hip_runtime.h>

typedef _Float16 f16;
typedef f16 f16x4 __attribute__((ext_vector_type(4)));
typedef f16 f16x8 __attribute__((ext_vector_type(8)));
typedef float f32x4 __attribute__((ext_vector_type(4)));

#define MFMA16(a, b, c) __builtin_amdgcn_mfma_f32_16x16x16f16((a), (b), (c), 0, 0, 0)
#define MFMA32(a, b, c) __builtin_amdgcn_mfma_f32_16x16x32_f16((a), (b), (c), 0, 0, 0)

struct Meta   { int pi[5], ci[5], ni[5]; };
struct EmbMap { int m[9]; };

// ---------------- LayerNorm(+temporal emb) -> f16, 4 rows/block ----------------
template <int CIN>
__global__ __launch_bounds__(256) void ln_kernel(
    const float* in, long lda, const float* __restrict__ emb,
    const float* __restrict__ lng, const float* __restrict__ lnb,
    f16* out, long ldo, EmbMap em) {
  long row = (long)blockIdx.x * 4 + (threadIdx.x >> 6);
  int t = (int)(row >> 15);  // B*Y*X = 32768
  int lane = threadIdx.x & 63;
  constexpr int NCH = CIN / 64;
  const float* xr = in + row * lda;
  const float* er = emb + (long)em.m[t] * CIN;
  float v[NCH];
  float s = 0.f;
#pragma unroll
  for (int i = 0; i < NCH; ++i) { int c = lane + (i << 6); v[i] = xr[c] + er[c]; s += v[i]; }
#pragma unroll
  for (int o = 32; o >= 1; o >>= 1) s += __shfl_xor(s, o);
  float mu = s * (1.f / CIN), ss = 0.f;
#pragma unroll
  for (int i = 0; i < NCH; ++i) { float d = v[i] - mu; ss += d * d; }
#pragma unroll
  for (int o = 32; o >= 1; o >>= 1) ss += __shfl_xor(ss, o);
  float inv = rsqrtf(ss * (1.f / CIN) + 1e-3f);
  f16* orow = out + row * ldo;
#pragma unroll
  for (int i = 0; i < NCH; ++i) {
    int c = lane + (i << 6);
    orow[c] = (f16)((v[i] - mu) * inv * lng[c] + lnb[c]);
  }
}

// ---------------- wqkv transpose+convert ----------------
template <int CIN>
__global__ __launch_bounds__(64) void wT_kernel(const float* __restrict__ wqkv,
                                                f16* __restrict__ wqkvT) {
  int j = blockIdx.x;
  int which = j / CIN, jj = j % CIN;
  const float* src = wqkv + (long)which * CIN * CIN + jj;
  f16* dst = wqkvT + (long)j * CIN;
  for (int c = threadIdx.x; c < CIN; c += 64) dst[c] = (f16)src[(long)c * CIN];
}

// ---------------- fused out-proj weights -> wocA[k/8][CO][8] layout ----------------
// wocA[((pm>>3)*CO + o)*8 + (pm&7)] = sum_c wo[mm][c]*cw[pm...][o], pm = p*CIN+mm
template <int CIN, int CO>
__global__ __launch_bounds__(256) void woc_kernel(
    const float* __restrict__ wo, const float* __restrict__ bo,
    const float* __restrict__ cw, const float* __restrict__ cb,
    f16* __restrict__ wocA, float* __restrict__ fb) {
  __shared__ float scw[4 * CIN];
  __shared__ float red[256];
  int o = blockIdx.x;
  for (int i = threadIdx.x; i < 4 * CIN; i += 256) scw[i] = cw[(long)i * CO + o];
  __syncthreads();
  for (int pm = threadIdx.x; pm < 4 * CIN; pm += 256) {
    int p = pm / CIN, mm = pm % CIN;
    const float* wr = wo + (long)mm * CIN;
    const float* sc = scw + p * CIN;
    float s = 0.f;
    for (int c = 0; c < CIN; ++c) s += wr[c] * sc[c];
    wocA[((long)(pm >> 3) * CO + o) * 8 + (pm & 7)] = (f16)s;
  }
  float part = 0.f;
  for (int i = threadIdx.x; i < 4 * CIN; i += 256) part += bo[i % CIN] * scw[i];
  red[threadIdx.x] = part;
  __syncthreads();
  for (int st = 128; st > 0; st >>= 1) {
    if (threadIdx.x < st) red[threadIdx.x] += red[threadIdx.x + st];
    __syncthreads();
  }
  if (threadIdx.x == 0) fb[o] = cb[o] + red[0];
}

// ---------------- QKV projection GEMM: weights in LDS, one block = one window --
template <int CIN>
__global__ __launch_bounds__(256) void proj_kernel(
    const f16* __restrict__ cur, long lda, const f16* __restrict__ wT,
    const float* __restrict__ bqkv, f16* __restrict__ gq, f16* __restrict__ gk,
    f16* __restrict__ gvt) {
  constexpr int KS = CIN / 32;
  constexpr int NT = CIN / 16;
  constexpr int C8 = CIN / 8;
  __shared__ f16 sB[CIN * CIN];
  int which = blockIdx.x;
  long win = blockIdx.y;                 // img*256 + wid
  long img = win >> 8;
  int wid = (int)(win & 255);
  int wy = wid >> 4, wx = wid & 15;
  int w = threadIdx.x >> 6, lane = threadIdx.x & 63;
  int r16 = lane & 15, kq = lane >> 4;

  int tok = w * 16 + r16;
  long orig = img * 16384 + (long)(wy * 8 + (tok >> 3)) * 128 + wx * 8 + (tok & 7);
  const f16* arow = cur + orig * lda + kq * 8;
  f16x8 a[KS];
#pragma unroll
  for (int ks = 0; ks < KS; ++ks) a[ks] = *(const f16x8*)(arow + ks * 32);

  const f16* wsrc = wT + (long)which * CIN * CIN;
  for (int idx = threadIdx.x; idx < CIN * C8; idx += 256) {
    int j = idx / C8, c8 = idx % C8;
    f16x8 v = *(const f16x8*)(wsrc + idx * 8);
    int off = ((j * CIN + c8 * 8) * 2) ^ ((j & 7) << 4);
    *(f16x8*)((char*)sB + off) = v;
  }
  __syncthreads();

  f32x4 acc[NT] = {};
#pragma unroll
  for (int ks = 0; ks < KS; ++ks) {
#pragma unroll
    for (int t = 0; t < NT; ++t) {
      int off = (((t * 16 + r16) * CIN + ks * 32 + kq * 8) * 2) ^ ((r16 & 7) << 4);
      f16x8 bb = *(const f16x8*)((char*)sB + off);
      acc[t] = MFMA32(a[ks], bb, acc[t]);
    }
  }
  __syncthreads();  // reuse sB as output staging

  if (which < 2) {
#pragma unroll
    for (int t = 0; t < NT; ++t) {
      float bias = bqkv[which * CIN + t * 16 + r16];
#pragma unroll
      for (int rg = 0; rg < 4; ++rg) {
        int r = w * 16 + kq * 4 + rg;
        int c = t * 16 + r16;
        int off = ((r * CIN + c) * 2) ^ ((r & 7) << 4);
        *(f16*)((char*)sB + off) = (f16)(acc[t][rg] + bias);
      }
    }
    __syncthreads();
    f16* dst = (which ? gk : gq) + win * 64 * CIN;
    for (int idx = threadIdx.x; idx < 64 * C8; idx += 256) {
      int r = idx / C8, c8 = idx % C8;
      int off = ((r * CIN + c8 * 8) * 2) ^ ((r & 7) << 4);
      f16x8 v = *(const f16x8*)((char*)sB + off);
      *(f16x8*)(dst + r * CIN + c8 * 8) = v;
    }
  } else {
#pragma unroll
    for (int t = 0; t < NT; ++t) {
      float bias = bqkv[2 * CIN + t * 16 + r16];
#pragma unroll
      for (int rg = 0; rg < 4; ++rg) {
        int c = t * 16 + r16;
        int pos = w * 16 + kq * 4 + rg;
        int off = ((c * 64 + pos) * 2) ^ ((c & 7) << 4);
        *(f16*)((char*)sB + off) = (f16)(acc[t][rg] + bias);
      }
    }
    __syncthreads();
    for (int c = threadIdx.x; c < CIN; c += 256) {
      f16* dst = gvt + (win * CIN + c) * 64;
#pragma unroll
      for (int p8 = 0; p8 < 8; ++p8) {
        int off = ((c * 64 + p8 * 8) * 2) ^ ((c & 7) << 4);
        *(f16x8*)(dst + p8 * 8) = *(const f16x8*)((char*)sB + off);
      }
    }
  }
}

// ---------------- fused window attention v3 ----------------
// One barrier/part (O double-buffered), MFMA32 scores(DH>=32)+down, reg softmax
// without max-subtraction (LN-bounded logits), per-ti softmax for low liveness.
template <int CIN, int DH, int CO>
__global__ __launch_bounds__(256) void attn_kernel(
    const f16* __restrict__ gq, const f16* __restrict__ gk,
    const f16* __restrict__ gvt, const f16* __restrict__ wocA,
    const float* __restrict__ fb, float* __restrict__ out, Meta m) {
  constexpr int NKS = DH / 16;
  constexpr int NK8 = DH / 32;
  constexpr int NK4 = (DH % 32) / 16;
  constexpr int CO4 = CO / 4;
  constexpr int NTC = CO4 / 16;
  constexpr int NKD = CIN / 32;
  constexpr float scale = (DH == 16) ? 0.25f : (DH == 32) ? 0.1767766952966369f
                                                          : 0.1443375672974064f;
  constexpr float escale = scale * 1.4426950408889634f;
  __shared__ f16 O[2][64 * CIN];

  int img = blockIdx.y;
  int sidx = img >> 1, b = img & 1;
  int wid = blockIdx.x;
  int wy = wid >> 4, wx = wid & 15;
  int h = threadIdx.x >> 6, lane = threadIdx.x & 63;
  int r16 = lane & 15, kq = lane >> 4;
  int fpi = m.pi[sidx], fci = m.ci[sidx], fni = m.ni[sidx];

  f32x4 dn[NTC][4] = {};

#pragma unroll
  for (int p = 0; p < 4; ++p) {
    int qfr = (p == 1) ? fpi : ((p == 3) ? fni : fci);
    int kfr = (p == 0) ? fpi : ((p == 2) ? fni : fci);
    long qwin = (long)((qfr * 2 + b) * 256 + wid);
    long kwin = (long)((kfr * 2 + b) * 256 + wid);

    // ---- K fragments + V fragments (prefetch) ----
    f16x8 kf8[4][NK8 ? NK8 : 1];
    f16x4 kf4[4][NK4 ? NK4 : 1];
#pragma unroll
    for (int tj = 0; tj < 4; ++tj) {
      const f16* kb = gk + (kwin * 64 + tj * 16 + r16) * CIN + h * DH;
      if constexpr (NK8 > 0)
#pragma unroll
        for (int n = 0; n < NK8; ++n)
          kf8[tj][n] = *(const f16x8*)(kb + n * 32 + kq * 8);
      if constexpr (NK4 > 0)
#pragma unroll
        for (int n = 0; n < NK4; ++n)
          kf4[tj][n] = *(const f16x4*)(kb + NK8 * 32 + n * 16 + kq * 4);
    }
    f16x4 va[NKS][4];
#pragma unroll
    for (int dt = 0; dt < NKS; ++dt)
#pragma unroll
      for (int jt = 0; jt < 4; ++jt)
        va[dt][jt] = *(const f16x4*)(gvt + (kwin * CIN + h * DH + dt * 16 + r16) * 64 +
                                     jt * 16 + kq * 4);

    // ---- scores + softmax per ti (S^T = K*Q^T; P lane-local) ----
    f16x4 pa[4][4];  // [tj][ti]
#pragma unroll
    for (int ti = 0; ti < 4; ++ti) {
      const f16* qb = gq + (qwin * 64 + ti * 16 + r16) * CIN + h * DH;
      f32x4 s4[4] = {};
      if constexpr (NK8 > 0) {
        f16x8 qf8[NK8];
#pragma unroll
        for (int n = 0; n < NK8; ++n) qf8[n] = *(const f16x8*)(qb + n * 32 + kq * 8);
#pragma unroll
        for (int tj = 0; tj < 4; ++tj)
#pragma unroll
          for (int n = 0; n < NK8; ++n) s4[tj] = MFMA32(kf8[tj][n], qf8[n], s4[tj]);
      }
      if constexpr (NK4 > 0) {
        f16x4 qf4[NK4];
#pragma unroll
        for (int n = 0; n < NK4; ++n)
          qf4[n] = *(const f16x4*)(qb + NK8 * 32 + n * 16 + kq * 4);
#pragma unroll
        for (int tj = 0; tj < 4; ++tj)
#pragma unroll
          for (int n = 0; n < NK4; ++n) s4[tj] = MFMA16(kf4[tj][n], qf4[n], s4[tj]);
      }
      float sum = 0.f;
#pragma unroll
      for (int tj = 0; tj < 4; ++tj)
#pragma unroll
        for (int rg = 0; rg < 4; ++rg) {
          float e = __builtin_amdgcn_exp2f(s4[tj][rg] * escale);
          s4[tj][rg] = e;
          sum += e;
        }
      sum += __shfl_xor(sum, 16);
      sum += __shfl_xor(sum, 32);
      float inv = 1.f / sum;
#pragma unroll
      for (int tj = 0; tj < 4; ++tj) {
        f16x4 pv;
#pragma unroll
        for (int rg = 0; rg < 4; ++rg) pv[rg] = (f16)(s4[tj][rg] * inv);
        pa[tj][ti] = pv;
      }
    }

    // ---- O^T = V^T * P^T -> LDS O[p&1] (XOR-swizzled) ----
    char* Ob = (char*)O[p & 1];
#pragma unroll
    for (int dt = 0; dt < NKS; ++dt) {
#pragma unroll
      for (int ti = 0; ti < 4; ++ti) {
        f32x4 po = {};
#pragma unroll
        for (int jt = 0; jt < 4; ++jt) po = MFMA16(va[dt][jt], pa[jt][ti], po);
        int i = ti * 16 + r16;
        int c0 = h * DH + dt * 16 + kq * 4;
        f16x4 pk;
#pragma unroll
        for (int rg = 0; rg < 4; ++rg) pk[rg] = (f16)po[rg];
        int off = ((i * CIN + c0) * 2) ^ ((i & 7) << 4);
        *(f16x4*)(Ob + off) = pk;
      }
    }
    __syncthreads();  // only barrier this part

    // ---- dn^T += woc_p^T * O^T  (MFMA32, lane-contiguous wocA reads) ----
#pragma unroll
    for (int ck = 0; ck < NKD; ++ck) {
      f16x8 ob[4];
#pragma unroll
      for (int ti = 0; ti < 4; ++ti) {
        int i = ti * 16 + r16;
        int off = ((i * CIN + ck * 32 + kq * 8) * 2) ^ ((i & 7) << 4);
        ob[ti] = *(const f16x8*)(Ob + off);
      }
      long pm = (long)(p * CIN + ck * 32 + kq * 8);
#pragma unroll
      for (int ot = 0; ot < NTC; ++ot) {
        f16x8 wa = *(const f16x8*)(wocA + ((pm >> 3) * CO + h * CO4 + ot * 16 + r16) * 8);
#pragma unroll
        for (int ti = 0; ti < 4; ++ti) dn[ot][ti] = MFMA32(wa, ob[ti], dn[ot][ti]);
      }
    }
  }

  // ---- store: relu(dn + fb), packed f32x4 ----
#pragma unroll
  for (int ot = 0; ot < NTC; ++ot) {
    f32x4 fb4 = *(const f32x4*)(fb + h * CO4 + ot * 16 + kq * 4);
#pragma unroll
    for (int ti = 0; ti < 4; ++ti) {
      int i = ti * 16 + r16;
      long gtok = (long)img * 16384 + (wy * 8 + (i >> 3)) * 128 + wx * 8 + (i & 7);
      f32x4 v;
#pragma unroll
      for (int rg = 0; rg < 4; ++rg) v[rg] = fmaxf(dn[ot][ti][rg] + fb4[rg], 0.f);
      *(f32x4*)(out + gtok * CO + h * CO4 + ot * 16 + kq * 4) = v;
    }
  }
}

extern "C" void kernel_launch(void* const* d_in, const int* in_sizes, int n_in,
                              void* d_out, int out_size, void* d_ws, size_t ws_size,
                              hipStream_t stream) {
  const float* x = (const float*)d_in[0];
#define PRM(l, k) ((const float*)d_in[1 + 9 * (l) + (k)])
  float* outCur = (float*)d_out;                 // [2,128,128,256]
  float* outL1 = (float*)d_out + 8388608;        // [5,2,128,128,128]

  char* ws = (char*)d_ws;
  const size_t OFF_B = 125829120ull;             // qkv arena
  const size_t OFF_W = OFF_B + 75497472ull;      // cur / accum1 arena
  f16* qkvbase = (f16*)ws;
  char* wsB = ws + OFF_B;
  float* accum1 = (float*)wsB;
  f16* wqkvT = (f16*)(ws + OFF_W);
  f16* wocA = (f16*)(ws + OFF_W + 262144);
  float* fb = (float*)(ws + OFF_W + 262144 + 524288);

  Meta m0 = {{0, 1, 3, 5, 6}, {1, 2, 4, 6, 7}, {2, 3, 5, 7, 8}};
  Meta m1 = {{0, 1, 2, 0, 0}, {1, 2, 3, 0, 0}, {2, 3, 4, 0, 0}};
  Meta m2 = {{0, 0, 0, 0, 0}, {1, 0, 0, 0, 0}, {2, 0, 0, 0, 0}};
  EmbMap em0 = {{0, 1, 2, 3, 4, 5, 6, 7, 8}};
  EmbMap em1 = {{1, 2, 4, 6, 7, 0, 0, 0, 0}};
  EmbMap em2 = {{2, 4, 6, 0, 0, 0, 0, 0, 0}};

  // ---------------- Level 0: CIN=64, DH=16, CO=128, TL=9, S=5 ----------------
  {
    constexpr int CIN = 64, DH = 16, CO = 128, TL = 9, S = 5;
    long ntok = (long)TL * 2 * 16384;
    f16 *gq = qkvbase, *gk = gq + ntok * CIN, *gvt = gk + ntok * CIN;
    f16* cur = (f16*)wsB;
    ln_kernel<CIN><<<dim3((unsigned)(ntok / 4)), 256, 0, stream>>>(
        x, CIN, PRM(0, 0), PRM(0, 1), PRM(0, 2), cur, CIN, em0);
    wT_kernel<CIN><<<dim3(3 * CIN), 64, 0, stream>>>(PRM(0, 3), wqkvT);
    woc_kernel<CIN, CO><<<dim3(CO), 256, 0, stream>>>(PRM(0, 5), PRM(0, 6), PRM(0, 7), PRM(0, 8), wocA, fb);
    proj_kernel<CIN><<<dim3(3, (unsigned)(ntok / 64)), 256, 0, stream>>>(
        cur, CIN, wqkvT, PRM(0, 4), gq, gk, gvt);
    attn_kernel<CIN, DH, CO><<<dim3(256, S * 2), 256, 0, stream>>>(
        gq, gk, gvt, wocA, fb, outL1, m0);
  }
  // ---------------- Level 1: CIN=128, DH=32, CO=192, TL=5, S=3 ----------------
  {
    constexpr int CIN = 128, DH = 32, CO = 192, TL = 5, S = 3;
    long ntok = (long)TL * 2 * 16384;
    f16 *gq = qkvbase, *gk = gq + ntok * CIN, *gvt = gk + ntok * CIN;
    f16* cur = (f16*)wsB;
    ln_kernel<CIN><<<dim3((unsigned)(ntok / 4)), 256, 0, stream>>>(
        outL1, CIN, PRM(1, 0), PRM(1, 1), PRM(1, 2), cur, CIN, em1);
    wT_kernel<CIN><<<dim3(3 * CIN), 64, 0, stream>>>(PRM(1, 3), wqkvT);
    woc_kernel<CIN, CO><<<dim3(CO), 256, 0, stream>>>(PRM(1, 5), PRM(1, 6), PRM(1, 7), PRM(1, 8), wocA, fb);
    proj_kernel<CIN><<<dim3(3, (unsigned)(ntok / 64)), 256, 0, stream>>>(
        cur, CIN, wqkvT, PRM(1, 4), gq, gk, gvt);
    attn_kernel<CIN, DH, CO><<<dim3(256, S * 2), 256, 0, stream>>>(
        gq, gk, gvt, wocA, fb, accum1, m1);
  }
  // ---------------- Level 2: CIN=192, DH=48, CO=256, TL=3, S=1 ----------------
  {
    constexpr int CIN = 192, DH = 48, CO = 256, TL = 3, S = 1;
    long ntok = (long)TL * 2 * 16384;
    f16 *gq = qkvbase, *gk = gq + ntok * CIN, *gvt = gk + ntok * CIN;
    f16* cur = (f16*)accum1;  // in-place LN: fp32 rows (stride 192) -> f16 (stride 384)
    ln_kernel<CIN><<<dim3((unsigned)(ntok / 4)), 256, 0, stream>>>(
        accum1, CIN, PRM(2, 0), PRM(2, 1), PRM(2, 2), cur, 384, em2);
    wT_kernel<CIN><<<dim3(3 * CIN), 64, 0, stream>>>(PRM(2, 3), wqkvT);
    woc_kernel<CIN, CO><<<dim3(CO), 256, 0, stream>>>(PRM(2, 5), PRM(2, 6), PRM(2, 7), PRM(2, 8), wocA, fb);
    proj_kernel<CIN><<<dim3(3, (unsigned)(ntok / 64)), 256, 0, stream>>>(
        cur, 384, wqkvT, PRM(2, 4), gq, gk, gvt);
    attn_kernel<CIN, DH, CO><<<dim3(256, S * 2), 256, 0, stream>>>(
        gq, gk, gvt, wocA, fb, outCur, m2);
  }
#undef PRM
}